// Round 1
// 2672.330 us; speedup vs baseline: 1.2596x; 1.2596x over previous
//
#include <hip/hip_runtime.h>

// MixLlamaMLP: y = (silu(x@Wg) * (x@Wu)) @ Wd
// B=4 S=2048 H=4096 I=11008, M = B*S = 8192. fp32 in/out, bf16 MFMA compute.
// R3: 256x256 8-phase pipelined GEMMs (T1 XCD swizzle + T2 st_16x32 LDS swizzle +
//     T3/T4 counted vmcnt(6) + T5 setprio). Gate/Up fused via 16-col interleaved W'.
#define M_ 8192
#define H_ 4096
#define I_ 11008

typedef __bf16  bf16x8  __attribute__((ext_vector_type(8)));
typedef float   floatx4 __attribute__((ext_vector_type(4)));

__device__ __forceinline__ unsigned short f2bf(float f) {
  unsigned int u = __builtin_bit_cast(unsigned int, f);
  u += 0x7fffu + ((u >> 16) & 1u);
  return (unsigned short)(u >> 16);
}

__device__ __forceinline__ void gl_lds16(const unsigned short* g, unsigned short* l) {
  __builtin_amdgcn_global_load_lds(
      (__attribute__((address_space(1))) void*)g,
      (__attribute__((address_space(3))) void*)l,
      16, 0, 0);
}

// ---------------- conversion kernels ----------------

__global__ void cvt_x_kernel(const float4* __restrict__ in, ushort4* __restrict__ out) {
  int i = blockIdx.x * blockDim.x + threadIdx.x;
  float4 v = in[i];
  out[i] = make_ushort4(f2bf(v.x), f2bf(v.y), f2bf(v.z), f2bf(v.w));
}

// in: fp32 [R][C] row-major -> out: bf16 [C][R] transpose+convert.
// mode 0: out row = c.  mode 1/2: gate/up 16-block interleave: row = 32*(c>>4) + (mode-1)*16 + (c&15)
__global__ void transpose_cvt_kernel(const float* __restrict__ in,
                                     unsigned short* __restrict__ out,
                                     int R, int C, int mode) {
  __shared__ float tile[32][33];
  int tx = threadIdx.x & 31;
  int ty = threadIdx.x >> 5;            // 0..7
  int c0 = blockIdx.x * 32;
  int r0 = blockIdx.y * 32;
#pragma unroll
  for (int i = 0; i < 32; i += 8)
    tile[ty + i][tx] = in[(size_t)(r0 + ty + i) * C + (c0 + tx)];
  __syncthreads();
#pragma unroll
  for (int i = 0; i < 32; i += 8) {
    int c = c0 + ty + i;
    int orow = mode ? (((c >> 4) << 5) + ((mode - 1) << 4) + (c & 15)) : c;
    out[(size_t)orow * R + (r0 + tx)] = f2bf(tile[tx][ty + i]);
  }
}

// ---------------- 256x256 8-phase K-loop (shared by both GEMMs) ----------------
// A tile: 256(M) x 64(K), B tile: 256(N) x 64(K), both row-major-K in global (ld = K stride).
// LDS per operand: 2 bufs x 2 halves x [128][64] bf16 (16 KiB/half), st_16x32 swizzled.
// 8 waves: wm = wave>>2 picks A half; wave's N cols = {half0: wn*32..+32} U {half1: wn*32..+32}.
__device__ __forceinline__ void kloop256(
    const unsigned short* __restrict__ Ag,   // + m0*ld
    const unsigned short* __restrict__ Bg,   // + n0*ld
    const int ld, const int nt,              // nt = K/64 (even)
    unsigned short* sA, unsigned short* sB,  // 32768 shorts each
    floatx4 (&acc)[8][4])
{
  const int tid  = threadIdx.x;
  const int w    = tid >> 6;
  const int l    = tid & 63;
  const int lr   = l & 15;
  const int quad = l >> 4;
  const int wm   = w >> 2;   // 0..1
  const int wn   = w & 3;    // 0..3

  // staging: linear LDS dest, inverse-swizzled global source (rule 21)
  long soff0, soff1;
  {
    int p0 = w * 1024 + l * 16;
    int p1 = 8192 + p0;
    int q0 = p0 & 1023; q0 ^= ((q0 >> 9) & 1) << 5;
    int q1 = p1 & 1023; q1 ^= ((q1 >> 9) & 1) << 5;
    long r0 = (long)(((p0 >> 10) >> 1) * 16 + (q0 >> 6));
    long c0 = (long)(((p0 >> 10) & 1) * 32 + ((q0 >> 1) & 31));
    long r1 = (long)(((p1 >> 10) >> 1) * 16 + (q1 >> 6));
    long c1 = (long)(((p1 >> 10) & 1) * 32 + ((q1 >> 1) & 31));
    soff0 = r0 * ld + c0;
    soff1 = r1 * ld + c1;
  }
  unsigned short* dA = sA + w * 512 + l * 8;
  unsigned short* dB = sB + w * 512 + l * 8;
  // swizzled per-lane fragment byte offset within a 1024B subtile
  const int po = (lr * 64 + quad * 16) ^ (((lr >> 3) & 1) << 5);

#define STAGE_A(BUFP, HALF, TILE)                                              \
  { const unsigned short* s_ = Ag + (size_t)((HALF) * 128) * ld + (TILE) * 64; \
    gl_lds16(s_ + soff0, dA + (BUFP) * 16384 + (HALF) * 8192);                 \
    gl_lds16(s_ + soff1, dA + (BUFP) * 16384 + (HALF) * 8192 + 4096); }
#define STAGE_B(BUFP, HALF, TILE)                                              \
  { const unsigned short* s_ = Bg + (size_t)((HALF) * 128) * ld + (TILE) * 64; \
    gl_lds16(s_ + soff0, dB + (BUFP) * 16384 + (HALF) * 8192);                 \
    gl_lds16(s_ + soff1, dB + (BUFP) * 16384 + (HALF) * 8192 + 4096); }
#define FRAGA(BUFP, SUB) \
  (*(const bf16x8*)((const char*)(sA + (BUFP) * 16384 + wm * 8192) + (SUB) * 1024 + po))
#define FRAGB(BUFP, HALF, SUB) \
  (*(const bf16x8*)((const char*)(sB + (BUFP) * 16384 + (HALF) * 8192) + (SUB) * 1024 + po))
#define LOAD_A(MQ, BUFP)                             \
  _Pragma("unroll") for (int ks = 0; ks < 2; ++ks)   \
  _Pragma("unroll") for (int mi = 0; mi < 4; ++mi)   \
    a[ks][mi] = FRAGA(BUFP, ((MQ) * 4 + mi) * 2 + ks);
#define LOAD_B(BB, NQ, BUFP)                         \
  _Pragma("unroll") for (int ks = 0; ks < 2; ++ks)   \
  _Pragma("unroll") for (int nj = 0; nj < 2; ++nj)   \
    BB[ks][nj] = FRAGB(BUFP, NQ, (wn * 2 + nj) * 2 + ks);
#define MFMA_Q(MQ, NQ, BB)                                                          \
  _Pragma("unroll") for (int ks = 0; ks < 2; ++ks)                                  \
  _Pragma("unroll") for (int mi = 0; mi < 4; ++mi)                                  \
  _Pragma("unroll") for (int nj = 0; nj < 2; ++nj)                                  \
    acc[(MQ) * 4 + mi][(NQ) * 2 + nj] = __builtin_amdgcn_mfma_f32_16x16x32_bf16(    \
        a[ks][mi], BB[ks][nj], acc[(MQ) * 4 + mi][(NQ) * 2 + nj], 0, 0, 0);
#define PHASE_MID()                                    \
  __builtin_amdgcn_s_barrier();                        \
  asm volatile("s_waitcnt lgkmcnt(0)" ::: "memory");   \
  __builtin_amdgcn_sched_barrier(0);                   \
  __builtin_amdgcn_s_setprio(1)
#define PHASE_END()                \
  __builtin_amdgcn_s_setprio(0);   \
  __builtin_amdgcn_s_barrier()

  // prologue: tile0 -> buf0 (all 4 units), tile1 -> buf1 (B0,B1,A0); A1 staged in loop ph1
  STAGE_B(0, 0, 0); STAGE_B(0, 1, 0); STAGE_A(0, 0, 0); STAGE_A(0, 1, 0);
  STAGE_B(1, 0, 1); STAGE_B(1, 1, 1); STAGE_A(1, 0, 1);
  asm volatile("s_waitcnt vmcnt(6)" ::: "memory");
  __builtin_amdgcn_s_barrier();

  bf16x8 a[2][4], b0[2][2], b1[2][2];
  const int ni = nt >> 1;
  for (int i = 0; i < ni; ++i) {
    const bool stg = (i + 1 < ni);
    const int t2 = 2 * i + 2, t3 = 2 * i + 3;

    // ph1: buf0 quadrant (mq0,nq0); stage buf1.A1 (tile 2i+1)
    LOAD_A(0, 0); LOAD_B(b0, 0, 0);
    STAGE_A(1, 1, 2 * i + 1);
    PHASE_MID(); MFMA_Q(0, 0, b0); PHASE_END();
    // ph2: (mq0,nq1); stage buf0.B0 (tile 2i+2)
    LOAD_B(b1, 1, 0);
    if (stg) STAGE_B(0, 0, t2);
    PHASE_MID(); MFMA_Q(0, 1, b1); PHASE_END();
    // ph3: (mq1,nq1); stage buf0.B1
    LOAD_A(1, 0);
    if (stg) STAGE_B(0, 1, t2);
    PHASE_MID(); MFMA_Q(1, 1, b1); PHASE_END();
    // ph4: (mq1,nq0); stage buf0.A0; counted vmcnt -> buf1 ready
    if (stg) STAGE_A(0, 0, t2);
    PHASE_MID(); MFMA_Q(1, 0, b0);
    __builtin_amdgcn_s_setprio(0);
    if (stg) { asm volatile("s_waitcnt vmcnt(6)" ::: "memory"); }
    else     { asm volatile("s_waitcnt vmcnt(0)" ::: "memory"); }
    __builtin_amdgcn_s_barrier();

    // ph5: buf1 (mq0,nq0); stage buf0.A1
    LOAD_A(0, 1); LOAD_B(b0, 0, 1);
    if (stg) STAGE_A(0, 1, t2);
    PHASE_MID(); MFMA_Q(0, 0, b0); PHASE_END();
    // ph6: (mq0,nq1); stage buf1.B0 (tile 2i+3)
    LOAD_B(b1, 1, 1);
    if (stg) STAGE_B(1, 0, t3);
    PHASE_MID(); MFMA_Q(0, 1, b1); PHASE_END();
    // ph7: (mq1,nq1); stage buf1.B1
    LOAD_A(1, 1);
    if (stg) STAGE_B(1, 1, t3);
    PHASE_MID(); MFMA_Q(1, 1, b1); PHASE_END();
    // ph8: (mq1,nq0); stage buf1.A0; counted vmcnt -> buf0 ready
    if (stg) STAGE_A(1, 0, t3);
    PHASE_MID(); MFMA_Q(1, 0, b0);
    __builtin_amdgcn_s_setprio(0);
    if (stg) { asm volatile("s_waitcnt vmcnt(6)" ::: "memory"); }
    __builtin_amdgcn_s_barrier();
  }
#undef STAGE_A
#undef STAGE_B
#undef FRAGA
#undef FRAGB
#undef LOAD_A
#undef LOAD_B
#undef MFMA_Q
#undef PHASE_MID
#undef PHASE_END
}

// ---------------- fused gate+up GEMM (interleaved W', fused silu*mul epilogue) ----------------
// W' bf16 [22016][4096]: row 32*(c>>4)+(c&15) = Wg col c, row +16 = Wu col c.
// A frag-pair (nj=0, nj=1) of a wave holds gate/up for the SAME act columns -> thread-local fuse.
__global__ __launch_bounds__(512, 2) void gemm_gateup_8p(
    const unsigned short* __restrict__ Xb,
    const unsigned short* __restrict__ Wp,
    unsigned short* __restrict__ Act) {
  __shared__ alignas(16) unsigned short sA[32768];
  __shared__ alignas(16) unsigned short sB[32768];

  const int nwg = gridDim.x;  // 2752, % 8 == 0
  const int pid = (blockIdx.x & 7) * (nwg >> 3) + (blockIdx.x >> 3);  // XCD swizzle (T1)
  const int NMT = M_ / 256;   // 32
  const int GN  = 2;
  const int grp = pid / (NMT * GN);
  const int rem = pid - grp * (NMT * GN);
  const int m0 = (rem % NMT) * 256;
  const int n0 = (grp * GN + rem / NMT) * 256;

  floatx4 acc[8][4] = {};
  kloop256(Xb + (size_t)m0 * H_, Wp + (size_t)n0 * H_, H_, H_ / 64, sA, sB, acc);

  const int tid  = threadIdx.x;
  const int l    = tid & 63;
  const int lr   = l & 15;
  const int quad = l >> 4;
  const int w    = tid >> 6;
  const int wm   = w >> 2;
  const int wn   = w & 3;
#pragma unroll
  for (int im = 0; im < 8; ++im) {
    const int row = m0 + wm * 128 + im * 16 + quad * 4;
#pragma unroll
    for (int nq = 0; nq < 2; ++nq) {
      const int col = (n0 >> 1) + nq * 64 + wn * 16 + lr;
#pragma unroll
      for (int r = 0; r < 4; ++r) {
        float g = acc[im][nq * 2][r];
        float u = acc[im][nq * 2 + 1][r];
        float s = g / (1.0f + __expf(-g));
        Act[(size_t)(row + r) * I_ + col] = f2bf(s * u);
      }
    }
  }
}

// ---------------- down GEMM ----------------
__global__ __launch_bounds__(512, 2) void gemm_down_8p(
    const unsigned short* __restrict__ Ab,
    const unsigned short* __restrict__ WdT,
    float* __restrict__ Y) {
  __shared__ alignas(16) unsigned short sA[32768];
  __shared__ alignas(16) unsigned short sB[32768];

  const int nwg = gridDim.x;  // 512, % 8 == 0
  const int pid = (blockIdx.x & 7) * (nwg >> 3) + (blockIdx.x >> 3);
  const int NNT = H_ / 256;   // 16
  const int GM  = 2;
  const int grp = pid / (NNT * GM);
  const int rem = pid - grp * (NNT * GM);
  const int n0 = (rem % NNT) * 256;
  const int m0 = (grp * GM + rem / NNT) * 256;

  floatx4 acc[8][4] = {};
  kloop256(Ab + (size_t)m0 * I_, WdT + (size_t)n0 * I_, I_, I_ / 64, sA, sB, acc);

  const int tid  = threadIdx.x;
  const int l    = tid & 63;
  const int lr   = l & 15;
  const int quad = l >> 4;
  const int w    = tid >> 6;
  const int wm   = w >> 2;
  const int wn   = w & 3;
#pragma unroll
  for (int im = 0; im < 8; ++im) {
    const int row = m0 + wm * 128 + im * 16 + quad * 4;
#pragma unroll
    for (int jn = 0; jn < 4; ++jn) {
      const int col = n0 + (jn >> 1) * 128 + wn * 32 + (jn & 1) * 16 + lr;
#pragma unroll
      for (int r = 0; r < 4; ++r)
        Y[(size_t)(row + r) * H_ + col] = acc[im][jn][r];
    }
  }
}

// ---------------- launch ----------------

extern "C" void kernel_launch(void* const* d_in, const int* in_sizes, int n_in,
                              void* d_out, int out_size, void* d_ws, size_t ws_size,
                              hipStream_t stream) {
  const float* x  = (const float*)d_in[0];
  const float* wg = (const float*)d_in[1];
  const float* wu = (const float*)d_in[2];
  const float* wd = (const float*)d_in[3];
  float* out = (float*)d_out;

  char* ws = (char*)d_ws;
  unsigned short* xb  = (unsigned short*)(ws);               // [M][H]      67,108,864 B
  unsigned short* wP  = (unsigned short*)(ws + 67108864);    // [2I][H]    180,355,072 B (interleaved)
  unsigned short* wdT = (unsigned short*)(ws + 247463936);   // [H][I]      90,177,536 B
  unsigned short* act = (unsigned short*)(ws + 337641472);   // [M][I]     180,355,072 B

  cvt_x_kernel<<<(M_ * H_ / 4) / 256, 256, 0, stream>>>((const float4*)x, (ushort4*)xb);
  transpose_cvt_kernel<<<dim3(I_ / 32, H_ / 32), 256, 0, stream>>>(wg, wP, H_, I_, 1);
  transpose_cvt_kernel<<<dim3(I_ / 32, H_ / 32), 256, 0, stream>>>(wu, wP, H_, I_, 2);
  transpose_cvt_kernel<<<dim3(H_ / 32, I_ / 32), 256, 0, stream>>>(wd, wdT, I_, H_, 0);

  gemm_gateup_8p<<<(M_ / 256) * ((2 * I_) / 256), 512, 0, stream>>>(xb, wP, act);
  gemm_down_8p<<<(M_ / 256) * (H_ / 256), 512, 0, stream>>>(act, wdT, out);
}

// Round 2
// 2566.712 us; speedup vs baseline: 1.3114x; 1.0411x over previous
//
#include <hip/hip_runtime.h>

// MixLlamaMLP: y = (silu(x@Wg) * (x@Wu)) @ Wd
// B=4 S=2048 H=4096 I=11008, M = B*S = 8192. fp32 in/out, bf16 MFMA compute.
// R4: cooperative L3 schedule. R3's chunked XCD swizzle desynchronized the 8 XCDs
//     -> X re-fetched 43x from HBM (FETCH 3.2GB). Now: super-group = 8 m-tiles x all
//     n-tiles, m-fastest, natural dispatch -> pid-consecutive blocks share one weight
//     panel across XCDs via L3; steady-state L3 set = W(180MB)+X-stripe(16MB) < 256MB.
#define M_ 8192
#define H_ 4096
#define I_ 11008

typedef __bf16  bf16x8  __attribute__((ext_vector_type(8)));
typedef float   floatx4 __attribute__((ext_vector_type(4)));

__device__ __forceinline__ unsigned short f2bf(float f) {
  unsigned int u = __builtin_bit_cast(unsigned int, f);
  u += 0x7fffu + ((u >> 16) & 1u);
  return (unsigned short)(u >> 16);
}

__device__ __forceinline__ void gl_lds16(const unsigned short* g, unsigned short* l) {
  __builtin_amdgcn_global_load_lds(
      (__attribute__((address_space(1))) void*)g,
      (__attribute__((address_space(3))) void*)l,
      16, 0, 0);
}

// ---------------- conversion kernels ----------------

__global__ void cvt_x_kernel(const float4* __restrict__ in, ushort4* __restrict__ out) {
  int i = blockIdx.x * blockDim.x + threadIdx.x;
  float4 v = in[i];
  out[i] = make_ushort4(f2bf(v.x), f2bf(v.y), f2bf(v.z), f2bf(v.w));
}

// in: fp32 [R][C] row-major -> out: bf16 [C][R] transpose+convert.
// mode 0: out row = c.  mode 1/2: gate/up 16-block interleave: row = 32*(c>>4) + (mode-1)*16 + (c&15)
__global__ void transpose_cvt_kernel(const float* __restrict__ in,
                                     unsigned short* __restrict__ out,
                                     int R, int C, int mode) {
  __shared__ float tile[32][33];
  int tx = threadIdx.x & 31;
  int ty = threadIdx.x >> 5;            // 0..7
  int c0 = blockIdx.x * 32;
  int r0 = blockIdx.y * 32;
#pragma unroll
  for (int i = 0; i < 32; i += 8)
    tile[ty + i][tx] = in[(size_t)(r0 + ty + i) * C + (c0 + tx)];
  __syncthreads();
#pragma unroll
  for (int i = 0; i < 32; i += 8) {
    int c = c0 + ty + i;
    int orow = mode ? (((c >> 4) << 5) + ((mode - 1) << 4) + (c & 15)) : c;
    out[(size_t)orow * R + (r0 + tx)] = f2bf(tile[tx][ty + i]);
  }
}

// ---------------- 256x256 8-phase K-loop (shared by both GEMMs) ----------------
// A tile: 256(M) x 64(K), B tile: 256(N) x 64(K), both row-major-K in global (ld = K stride).
// LDS per operand: 2 bufs x 2 halves x [128][64] bf16 (16 KiB/half), st_16x32 swizzled.
// 8 waves: wm = wave>>2 picks A half; wave's N cols = {half0: wn*32..+32} U {half1: wn*32..+32}.
__device__ __forceinline__ void kloop256(
    const unsigned short* __restrict__ Ag,   // + m0*ld
    const unsigned short* __restrict__ Bg,   // + n0*ld
    const int ld, const int nt,              // nt = K/64 (even)
    unsigned short* sA, unsigned short* sB,  // 32768 shorts each
    floatx4 (&acc)[8][4])
{
  const int tid  = threadIdx.x;
  const int w    = tid >> 6;
  const int l    = tid & 63;
  const int lr   = l & 15;
  const int quad = l >> 4;
  const int wm   = w >> 2;   // 0..1
  const int wn   = w & 3;    // 0..3

  // staging: linear LDS dest, inverse-swizzled global source (rule 21)
  long soff0, soff1;
  {
    int p0 = w * 1024 + l * 16;
    int p1 = 8192 + p0;
    int q0 = p0 & 1023; q0 ^= ((q0 >> 9) & 1) << 5;
    int q1 = p1 & 1023; q1 ^= ((q1 >> 9) & 1) << 5;
    long r0 = (long)(((p0 >> 10) >> 1) * 16 + (q0 >> 6));
    long c0 = (long)(((p0 >> 10) & 1) * 32 + ((q0 >> 1) & 31));
    long r1 = (long)(((p1 >> 10) >> 1) * 16 + (q1 >> 6));
    long c1 = (long)(((p1 >> 10) & 1) * 32 + ((q1 >> 1) & 31));
    soff0 = r0 * ld + c0;
    soff1 = r1 * ld + c1;
  }
  unsigned short* dA = sA + w * 512 + l * 8;
  unsigned short* dB = sB + w * 512 + l * 8;
  // swizzled per-lane fragment byte offset within a 1024B subtile
  const int po = (lr * 64 + quad * 16) ^ (((lr >> 3) & 1) << 5);

#define STAGE_A(BUFP, HALF, TILE)                                              \
  { const unsigned short* s_ = Ag + (size_t)((HALF) * 128) * ld + (TILE) * 64; \
    gl_lds16(s_ + soff0, dA + (BUFP) * 16384 + (HALF) * 8192);                 \
    gl_lds16(s_ + soff1, dA + (BUFP) * 16384 + (HALF) * 8192 + 4096); }
#define STAGE_B(BUFP, HALF, TILE)                                              \
  { const unsigned short* s_ = Bg + (size_t)((HALF) * 128) * ld + (TILE) * 64; \
    gl_lds16(s_ + soff0, dB + (BUFP) * 16384 + (HALF) * 8192);                 \
    gl_lds16(s_ + soff1, dB + (BUFP) * 16384 + (HALF) * 8192 + 4096); }
#define FRAGA(BUFP, SUB) \
  (*(const bf16x8*)((const char*)(sA + (BUFP) * 16384 + wm * 8192) + (SUB) * 1024 + po))
#define FRAGB(BUFP, HALF, SUB) \
  (*(const bf16x8*)((const char*)(sB + (BUFP) * 16384 + (HALF) * 8192) + (SUB) * 1024 + po))
#define LOAD_A(MQ, BUFP)                             \
  _Pragma("unroll") for (int ks = 0; ks < 2; ++ks)   \
  _Pragma("unroll") for (int mi = 0; mi < 4; ++mi)   \
    a[ks][mi] = FRAGA(BUFP, ((MQ) * 4 + mi) * 2 + ks);
#define LOAD_B(BB, NQ, BUFP)                         \
  _Pragma("unroll") for (int ks = 0; ks < 2; ++ks)   \
  _Pragma("unroll") for (int nj = 0; nj < 2; ++nj)   \
    BB[ks][nj] = FRAGB(BUFP, NQ, (wn * 2 + nj) * 2 + ks);
#define MFMA_Q(MQ, NQ, BB)                                                          \
  _Pragma("unroll") for (int ks = 0; ks < 2; ++ks)                                  \
  _Pragma("unroll") for (int mi = 0; mi < 4; ++mi)                                  \
  _Pragma("unroll") for (int nj = 0; nj < 2; ++nj)                                  \
    acc[(MQ) * 4 + mi][(NQ) * 2 + nj] = __builtin_amdgcn_mfma_f32_16x16x32_bf16(    \
        a[ks][mi], BB[ks][nj], acc[(MQ) * 4 + mi][(NQ) * 2 + nj], 0, 0, 0);
#define PHASE_MID()                                    \
  __builtin_amdgcn_s_barrier();                        \
  asm volatile("s_waitcnt lgkmcnt(0)" ::: "memory");   \
  __builtin_amdgcn_sched_barrier(0);                   \
  __builtin_amdgcn_s_setprio(1)
#define PHASE_END()                \
  __builtin_amdgcn_s_setprio(0);   \
  __builtin_amdgcn_s_barrier()

  // prologue: tile0 -> buf0 (all 4 units), tile1 -> buf1 (B0,B1,A0); A1 staged in loop ph1
  STAGE_B(0, 0, 0); STAGE_B(0, 1, 0); STAGE_A(0, 0, 0); STAGE_A(0, 1, 0);
  STAGE_B(1, 0, 1); STAGE_B(1, 1, 1); STAGE_A(1, 0, 1);
  asm volatile("s_waitcnt vmcnt(6)" ::: "memory");
  __builtin_amdgcn_s_barrier();

  bf16x8 a[2][4], b0[2][2], b1[2][2];
  const int ni = nt >> 1;
  for (int i = 0; i < ni; ++i) {
    const bool stg = (i + 1 < ni);
    const int t2 = 2 * i + 2, t3 = 2 * i + 3;

    // ph1: buf0 quadrant (mq0,nq0); stage buf1.A1 (tile 2i+1)
    LOAD_A(0, 0); LOAD_B(b0, 0, 0);
    STAGE_A(1, 1, 2 * i + 1);
    PHASE_MID(); MFMA_Q(0, 0, b0); PHASE_END();
    // ph2: (mq0,nq1); stage buf0.B0 (tile 2i+2)
    LOAD_B(b1, 1, 0);
    if (stg) STAGE_B(0, 0, t2);
    PHASE_MID(); MFMA_Q(0, 1, b1); PHASE_END();
    // ph3: (mq1,nq1); stage buf0.B1
    LOAD_A(1, 0);
    if (stg) STAGE_B(0, 1, t2);
    PHASE_MID(); MFMA_Q(1, 1, b1); PHASE_END();
    // ph4: (mq1,nq0); stage buf0.A0; counted vmcnt -> buf1 ready
    if (stg) STAGE_A(0, 0, t2);
    PHASE_MID(); MFMA_Q(1, 0, b0);
    __builtin_amdgcn_s_setprio(0);
    if (stg) { asm volatile("s_waitcnt vmcnt(6)" ::: "memory"); }
    else     { asm volatile("s_waitcnt vmcnt(0)" ::: "memory"); }
    __builtin_amdgcn_s_barrier();

    // ph5: buf1 (mq0,nq0); stage buf0.A1
    LOAD_A(0, 1); LOAD_B(b0, 0, 1);
    if (stg) STAGE_A(0, 1, t2);
    PHASE_MID(); MFMA_Q(0, 0, b0); PHASE_END();
    // ph6: (mq0,nq1); stage buf1.B0 (tile 2i+3)
    LOAD_B(b1, 1, 1);
    if (stg) STAGE_B(1, 0, t3);
    PHASE_MID(); MFMA_Q(0, 1, b1); PHASE_END();
    // ph7: (mq1,nq1); stage buf1.B1
    LOAD_A(1, 1);
    if (stg) STAGE_B(1, 1, t3);
    PHASE_MID(); MFMA_Q(1, 1, b1); PHASE_END();
    // ph8: (mq1,nq0); stage buf1.A0; counted vmcnt -> buf0 ready
    if (stg) STAGE_A(1, 0, t3);
    PHASE_MID(); MFMA_Q(1, 0, b0);
    __builtin_amdgcn_s_setprio(0);
    if (stg) { asm volatile("s_waitcnt vmcnt(6)" ::: "memory"); }
    __builtin_amdgcn_s_barrier();
  }
#undef STAGE_A
#undef STAGE_B
#undef FRAGA
#undef FRAGB
#undef LOAD_A
#undef LOAD_B
#undef MFMA_Q
#undef PHASE_MID
#undef PHASE_END
}

// ---------------- fused gate+up GEMM (interleaved W', fused silu*mul epilogue) ----------------
// W' bf16 [22016][4096]: row 32*(c>>4)+(c&15) = Wg col c, row +16 = Wu col c.
// A frag-pair (nj=0, nj=1) of a wave holds gate/up for the SAME act columns -> thread-local fuse.
__global__ __launch_bounds__(512, 2) void gemm_gateup_8p(
    const unsigned short* __restrict__ Xb,
    const unsigned short* __restrict__ Wp,
    unsigned short* __restrict__ Act) {
  __shared__ alignas(16) unsigned short sA[32768];
  __shared__ alignas(16) unsigned short sB[32768];

  // cooperative schedule: super-group = 8 m-tiles x all 86 n-tiles, m-fastest.
  // pid-consecutive blocks (different XCDs) share one weight panel -> L3 broadcast;
  // steady-state L3: W'(180MB) + X-stripe(16MB) resident. 2752 = 4 x (8*86).
  const int pid = blockIdx.x;
  const int NN  = (2 * I_) / 256;    // 86
  const int bpg = 8 * NN;            // 688
  const int sg  = pid / bpg;
  const int rem = pid - sg * bpg;
  const int m0 = (sg * 8 + (rem & 7)) * 256;
  const int n0 = (rem >> 3) * 256;

  floatx4 acc[8][4] = {};
  kloop256(Xb + (size_t)m0 * H_, Wp + (size_t)n0 * H_, H_, H_ / 64, sA, sB, acc);

  const int tid  = threadIdx.x;
  const int l    = tid & 63;
  const int lr   = l & 15;
  const int quad = l >> 4;
  const int w    = tid >> 6;
  const int wm   = w >> 2;
  const int wn   = w & 3;
#pragma unroll
  for (int im = 0; im < 8; ++im) {
    const int row = m0 + wm * 128 + im * 16 + quad * 4;
#pragma unroll
    for (int nq = 0; nq < 2; ++nq) {
      const int col = (n0 >> 1) + nq * 64 + wn * 16 + lr;
#pragma unroll
      for (int r = 0; r < 4; ++r) {
        float g = acc[im][nq * 2][r];
        float u = acc[im][nq * 2 + 1][r];
        float s = g / (1.0f + __expf(-g));
        Act[(size_t)(row + r) * I_ + col] = f2bf(s * u);
      }
    }
  }
}

// ---------------- down GEMM ----------------
__global__ __launch_bounds__(512, 2) void gemm_down_8p(
    const unsigned short* __restrict__ Ab,
    const unsigned short* __restrict__ WdT,
    float* __restrict__ Y) {
  __shared__ alignas(16) unsigned short sA[32768];
  __shared__ alignas(16) unsigned short sB[32768];

  // same cooperative schedule: super-group = 8 m-tiles x all 16 n-tiles, m-fastest.
  // WdT (90MB) L3-resident; Act stripe streamed once. 512 = 4 x (8*16).
  const int pid = blockIdx.x;
  const int NN  = H_ / 256;          // 16
  const int bpg = 8 * NN;            // 128
  const int sg  = pid / bpg;
  const int rem = pid - sg * bpg;
  const int m0 = (sg * 8 + (rem & 7)) * 256;
  const int n0 = (rem >> 3) * 256;

  floatx4 acc[8][4] = {};
  kloop256(Ab + (size_t)m0 * I_, WdT + (size_t)n0 * I_, I_, I_ / 64, sA, sB, acc);

  const int tid  = threadIdx.x;
  const int l    = tid & 63;
  const int lr   = l & 15;
  const int quad = l >> 4;
  const int w    = tid >> 6;
  const int wm   = w >> 2;
  const int wn   = w & 3;
#pragma unroll
  for (int im = 0; im < 8; ++im) {
    const int row = m0 + wm * 128 + im * 16 + quad * 4;
#pragma unroll
    for (int jn = 0; jn < 4; ++jn) {
      const int col = n0 + (jn >> 1) * 128 + wn * 32 + (jn & 1) * 16 + lr;
#pragma unroll
      for (int r = 0; r < 4; ++r)
        Y[(size_t)(row + r) * H_ + col] = acc[im][jn][r];
    }
  }
}

// ---------------- launch ----------------

extern "C" void kernel_launch(void* const* d_in, const int* in_sizes, int n_in,
                              void* d_out, int out_size, void* d_ws, size_t ws_size,
                              hipStream_t stream) {
  const float* x  = (const float*)d_in[0];
  const float* wg = (const float*)d_in[1];
  const float* wu = (const float*)d_in[2];
  const float* wd = (const float*)d_in[3];
  float* out = (float*)d_out;

  char* ws = (char*)d_ws;
  unsigned short* xb  = (unsigned short*)(ws);               // [M][H]      67,108,864 B
  unsigned short* wP  = (unsigned short*)(ws + 67108864);    // [2I][H]    180,355,072 B (interleaved)
  unsigned short* wdT = (unsigned short*)(ws + 247463936);   // [H][I]      90,177,536 B
  unsigned short* act = (unsigned short*)(ws + 337641472);   // [M][I]     180,355,072 B

  cvt_x_kernel<<<(M_ * H_ / 4) / 256, 256, 0, stream>>>((const float4*)x, (ushort4*)xb);
  transpose_cvt_kernel<<<dim3(I_ / 32, H_ / 32), 256, 0, stream>>>(wg, wP, H_, I_, 1);
  transpose_cvt_kernel<<<dim3(I_ / 32, H_ / 32), 256, 0, stream>>>(wu, wP, H_, I_, 2);
  transpose_cvt_kernel<<<dim3(H_ / 32, I_ / 32), 256, 0, stream>>>(wd, wdT, I_, H_, 0);

  gemm_gateup_8p<<<(M_ / 256) * ((2 * I_) / 256), 512, 0, stream>>>(xb, wP, act);
  gemm_down_8p<<<(M_ / 256) * (H_ / 256), 512, 0, stream>>>(act, wdT, out);
}